// Round 6
// baseline (129.646 us; speedup 1.0000x reference)
//
#include <hip/hip_runtime.h>

#define RELS 237
#define DIM 128
#define CH 64           // triples per chunk
#define MAXCHUNK 489    // sum ceil(c_r/64) <= (16384 + 237*63)/64
#define EPS 1e-12f

typedef __attribute__((ext_vector_type(8))) short bf16x8;
typedef __attribute__((ext_vector_type(4))) float f32x4;

// ws layout (int32):
//   [0, 237)     : per-relation counts (zeroed by memsetAsync, which covers [0,256))
//   [255]        : last-block ticket   (zeroed by same memset)
//   [300]        : n_chunks
//   [320, 576)   : per-relation exclusive offsets
//   [576, 832)   : per-relation atomic cursors
//   [1024, 1024+MAXCHUNK) : chunk worklist, entry = (r<<20)|(base<<6)|(len-1)
//   [2048, 2048+N): triple indices grouped by relation

__device__ __forceinline__ unsigned short f2bf(float f) {
    unsigned int u = __float_as_uint(f);
    u = (u + 0x7fffu + ((u >> 16) & 1u)) >> 16;   // RNE
    return (unsigned short)u;
}

// Histogram (global atomics) + last-done block performs scan & worklist emit.
// Counts are re-read with atomicAdd(p,0) so the read is device-coherent
// (plain loads could hit a stale per-XCD L2 line).
__global__ void k_count_scan(const int* __restrict__ r_typ, int* __restrict__ ws, int n) {
    __shared__ int scn[256];
    __shared__ int amLast;
    const int t = threadIdx.x;
    const int i = blockIdx.x * blockDim.x + t;
    if (i < n) atomicAdd(&ws[r_typ[i]], 1);
    __threadfence();
    if (t == 0) amLast = (atomicAdd(&ws[255], 1) == (int)gridDim.x - 1);
    __syncthreads();
    if (!amLast) return;

    const int c = (t < RELS) ? atomicAdd(&ws[t], 0) : 0;
    scn[t] = c; __syncthreads();
    #pragma unroll
    for (int off = 1; off < 256; off <<= 1) {
        int v = (t >= off) ? scn[t - off] : 0;
        __syncthreads();
        scn[t] += v; __syncthreads();
    }
    const int base = scn[t] - c;
    if (t < RELS) { ws[320 + t] = base; ws[576 + t] = base; }
    const int nch = (c + CH - 1) >> 6;
    __syncthreads();
    scn[t] = nch; __syncthreads();
    #pragma unroll
    for (int off = 1; off < 256; off <<= 1) {
        int v = (t >= off) ? scn[t - off] : 0;
        __syncthreads();
        scn[t] += v; __syncthreads();
    }
    const int choff = scn[t] - nch;
    if (t == 255) ws[300] = scn[255];
    for (int j = 0; j < nch; ++j) {
        int cb  = base + j * CH;
        int len = c - j * CH; if (len > CH) len = CH;
        ws[1024 + choff + j] = (t << 20) | (cb << 6) | (len - 1);
    }
}

__global__ void k_scatter(const int* __restrict__ r_typ, int* __restrict__ ws, int n) {
    int i = blockIdx.x * blockDim.x + threadIdx.x;
    if (i < n) {
        int pos = atomicAdd(&ws[576 + r_typ[i]], 1);
        ws[2048 + pos] = i;
    }
}

// One workgroup per 64-triple chunk of one relation. MFMA bf16 16x16x32,
// fp32 accumulate. A = h (M=64), B = R^T via direct row reads.
// LDS: Rb bf16[128][136] @0 (34816B), Hb bf16[64][136] @34816 (17408B),
// sidx @52224 (256B). Pp f32[64][132] (33792B) aliases dead Rb after mfma.
// 52.5KB/block -> 3 blocks/CU; all <=489 blocks co-resident.
__global__ __launch_bounds__(256, 3) void relgemm(
    const float* __restrict__ ent,
    const int*   __restrict__ h_ids,
    const int*   __restrict__ t_ids,
    const int*   __restrict__ ws,
    float*       __restrict__ out)
{
    __shared__ char smem[52480];
    unsigned short* Rb = (unsigned short*)smem;
    unsigned short* Hb = (unsigned short*)(smem + 34816);
    int*  sidx = (int*)(smem + 52224);
    float* Pp  = (float*)smem;

    const int cid = blockIdx.x;
    if (cid >= ws[300]) return;
    const int e    = ws[1024 + cid];
    const int r    = e >> 20;
    const int base = (e >> 6) & 16383;
    const int len  = (e & 63) + 1;
    const int* sorted = ws + 2048;

    const int tid  = threadIdx.x;
    const int lane = tid & 63;
    const int w    = tid >> 6;

    if (tid < CH) {
        int tc = tid < len ? tid : len - 1;
        sidx[tid] = sorted[base + tc];
    }
    __syncthreads();

    // ---- stage R (64KB fp32 -> 32KB bf16, padded stride 136 shorts)
    const float4* Rg = (const float4*)ent + ((long)r << 12);
    #pragma unroll
    for (int s = 0; s < 16; ++s) {
        int g = s * 256 + tid;
        int row = g >> 5, c4 = g & 31;
        float4 v = Rg[g];
        ushort4 b; b.x = f2bf(v.x); b.y = f2bf(v.y); b.z = f2bf(v.z); b.w = f2bf(v.w);
        *(ushort4*)(Rb + row * 136 + c4 * 4) = b;
    }
    // ---- stage h rows (64 x 512B fp32 -> bf16)
    #pragma unroll
    for (int s = 0; s < 8; ++s) {
        int g = s * 256 + tid;
        int trow = g >> 5, c4 = g & 31;
        int hid = h_ids[sidx[trow]];
        float4 v = ((const float4*)ent)[((long)hid << 5) + c4];
        ushort4 b; b.x = f2bf(v.x); b.y = f2bf(v.y); b.z = f2bf(v.z); b.w = f2bf(v.w);
        *(ushort4*)(Hb + trow * 136 + c4 * 4) = b;
    }
    __syncthreads();

    // ---- MFMA: wave w owns output cols [w*32, w*32+32); 4 M-tiles x 2 N-tiles
    const int q = lane >> 4, cc = lane & 15;
    const unsigned short* Ap0 = Hb + cc * 136 + q * 8;
    const unsigned short* Bp0 = Rb + (w * 32 + cc) * 136 + q * 8;
    const unsigned short* Bp1 = Rb + (w * 32 + 16 + cc) * 136 + q * 8;

    f32x4 acc[4][2];
    #pragma unroll
    for (int mt = 0; mt < 4; ++mt)
        #pragma unroll
        for (int nt = 0; nt < 2; ++nt)
            acc[mt][nt] = (f32x4){0.f, 0.f, 0.f, 0.f};

    #pragma unroll
    for (int ks = 0; ks < 4; ++ks) {
        bf16x8 B0 = *(const bf16x8*)(Bp0 + ks * 32);
        bf16x8 B1 = *(const bf16x8*)(Bp1 + ks * 32);
        #pragma unroll
        for (int mt = 0; mt < 4; ++mt) {
            bf16x8 A = *(const bf16x8*)(Ap0 + mt * 16 * 136 + ks * 32);
            acc[mt][0] = __builtin_amdgcn_mfma_f32_16x16x32_bf16(A, B0, acc[mt][0], 0, 0, 0);
            acc[mt][1] = __builtin_amdgcn_mfma_f32_16x16x32_bf16(A, B1, acc[mt][1], 0, 0, 0);
        }
    }
    __syncthreads();   // Rb dead; Pp aliases it

    // ---- write prod to LDS: D layout col=lane&15, row=(lane>>4)*4+reg
    #pragma unroll
    for (int mt = 0; mt < 4; ++mt)
        #pragma unroll
        for (int reg = 0; reg < 4; ++reg) {
            int m0 = mt * 16 + q * 4 + reg;
            Pp[m0 * 132 + w * 32      + cc] = acc[mt][0][reg];
            Pp[m0 * 132 + w * 32 + 16 + cc] = acc[mt][1][reg];
        }
    __syncthreads();

    // ---- epilogue: out = sqrt(2 - 2*<p,t>/(|p||t|)); wave w owns triples w*16..+15
    #pragma unroll
    for (int tt = 0; tt < 16; ++tt) {
        int t   = w * 16 + tt;
        int idx = sidx[t];
        int trow = __builtin_amdgcn_readfirstlane(t_ids[idx]);
        const float* tv = ent + ((long)trow << 7);
        float tv0 = tv[lane], tv1 = tv[lane + 64];
        float p0 = Pp[t * 132 + lane], p1 = Pp[t * 132 + 64 + lane];
        float sp  = p0 * p0 + p1 * p1;
        float st  = tv0 * tv0 + tv1 * tv1;
        float spt = p0 * tv0 + p1 * tv1;
        #pragma unroll
        for (int m = 32; m >= 1; m >>= 1) {
            sp  += __shfl_xor(sp,  m, 64);
            st  += __shfl_xor(st,  m, 64);
            spt += __shfl_xor(spt, m, 64);
        }
        if (lane == 0 && t < len) {
            float npn = fmaxf(sqrtf(sp), EPS);
            float ntn = fmaxf(sqrtf(st), EPS);
            float v   = 2.0f - 2.0f * (spt / (npn * ntn));
            out[idx] = sqrtf(fmaxf(v, 0.0f));
        }
    }
}

extern "C" void kernel_launch(void* const* d_in, const int* in_sizes, int n_in,
                              void* d_out, int out_size, void* d_ws, size_t ws_size,
                              hipStream_t stream) {
    const float* ent   = (const float*)d_in[0];
    const int*   h_ids = (const int*)d_in[1];
    const int*   r_typ = (const int*)d_in[2];
    const int*   t_ids = (const int*)d_in[3];
    float* out = (float*)d_out;
    int*   ws  = (int*)d_ws;
    const int n = in_sizes[1];
    const int nb = (n + 255) / 256;

    hipMemsetAsync(ws, 0, 1024, stream);   // counts + ticket (graph-capture-safe)
    hipLaunchKernelGGL(k_count_scan, dim3(nb),       dim3(256), 0, stream, r_typ, ws, n);
    hipLaunchKernelGGL(k_scatter,    dim3(nb),       dim3(256), 0, stream, r_typ, ws, n);
    hipLaunchKernelGGL(relgemm,      dim3(MAXCHUNK), dim3(256), 0, stream,
                       ent, h_ids, t_ids, ws, out);
}

// Round 7
// 122.198 us; speedup vs baseline: 1.0610x; 1.0610x over previous
//
#include <hip/hip_runtime.h>

#define RELS 237
#define DIM 128
#define CH 32           // triples per chunk
#define MAXCHUNK 742    // sum ceil(c_r/32) <= (16384 + 237*31)/32
#define PREPB 64        // prep grid: 64 blocks, trivially co-resident on 256 CUs
#define EPS 1e-12f

typedef __attribute__((ext_vector_type(8))) short bf16x8;
typedef __attribute__((ext_vector_type(4))) float f32x4;

// ws layout (int32):
//   [0, 237)     : per-relation counts   (zeroed by memsetAsync)
//   [254]        : barrier ticket        (zeroed)
//   [512, 749)   : per-relation scatter cursors (zeroed)
//   [1000]       : n_chunks
//   [1024, 1024+MAXCHUNK) : chunk worklist, entry = (r<<20)|(base<<6)|len
//   [2048, 2048+N): triple indices grouped by relation
// memsetAsync zeroes [0, 1024) ints = 4096 B.

__device__ __forceinline__ unsigned short f2bf(float f) {
    unsigned int u = __float_as_uint(f);
    u = (u + 0x7fffu + ((u >> 16) & 1u)) >> 16;   // RNE
    return (unsigned short)u;
}

// Single prep kernel, 64 blocks x 256 threads:
//   A: LDS histogram -> one global atomicAdd per (block, relation)
//   spin barrier (64 blocks always co-resident -> deadlock-free)
//   B: every block re-reads counts coherently + local LDS scan (redundant,
//      no 2nd barrier); block 0 emits chunk worklist + n_chunks
//   C: grid-stride scatter via LDS offsets + global atomic cursors
// Cross-block data flows only through device-scope atomics; plain stores
// (worklist, sorted list) are consumed by the NEXT dispatch only.
__global__ __launch_bounds__(256) void k_prep(const int* __restrict__ r_typ,
                                              int* __restrict__ ws, int n) {
    __shared__ int hist[256];
    __shared__ int offs[256];
    __shared__ int scn[256];
    const int t = threadIdx.x;
    hist[t] = 0;
    __syncthreads();

    // ---- A: count
    for (int i = blockIdx.x * 256 + t; i < n; i += PREPB * 256)
        atomicAdd(&hist[r_typ[i]], 1);
    __syncthreads();
    if (t < RELS && hist[t] > 0) atomicAdd(&ws[t], hist[t]);

    // ---- barrier
    __syncthreads();
    __threadfence();
    if (t == 0) {
        atomicAdd(&ws[254], 1);
        while (atomicAdd(&ws[254], 0) < PREPB) __builtin_amdgcn_s_sleep(2);
    }
    __syncthreads();
    __threadfence();

    // ---- B: coherent re-read + local scan
    const int c = (t < RELS) ? atomicAdd(&ws[t], 0) : 0;
    scn[t] = c; __syncthreads();
    #pragma unroll
    for (int off = 1; off < 256; off <<= 1) {
        int v = (t >= off) ? scn[t - off] : 0;
        __syncthreads();
        scn[t] += v; __syncthreads();
    }
    offs[t] = scn[t] - c;
    __syncthreads();

    if (blockIdx.x == 0) {
        const int nch = (c + CH - 1) >> 5;
        scn[t] = nch; __syncthreads();
        #pragma unroll
        for (int off = 1; off < 256; off <<= 1) {
            int v = (t >= off) ? scn[t - off] : 0;
            __syncthreads();
            scn[t] += v; __syncthreads();
        }
        const int choff = scn[t] - nch;
        if (t == 255) ws[1000] = scn[255];
        for (int j = 0; j < nch; ++j) {
            int cb  = offs[t] + j * CH;
            int len = c - j * CH; if (len > CH) len = CH;
            ws[1024 + choff + j] = (t << 20) | (cb << 6) | len;
        }
    }

    // ---- C: scatter
    for (int i = blockIdx.x * 256 + t; i < n; i += PREPB * 256) {
        int rr  = r_typ[i];
        int pos = offs[rr] + atomicAdd(&ws[512 + rr], 1);
        ws[2048 + pos] = i;
    }
}

// One workgroup per 32-triple chunk of one relation. MFMA bf16 16x16x32:
// A = h (M=32 triples), B = R^T via direct row reads (B wants contiguous-K
// per lane = contiguous-d = R row order; no transpose). fp32 accumulate.
// LDS: Rb bf16[128][136] @0 (34816B), Hb bf16[32][136] @34816 (8704B),
// sidx @43520 (128B); Pp f32[32][132] @0 aliases dead Rb after mfma barrier.
__global__ __launch_bounds__(256, 3) void relgemm(
    const float* __restrict__ ent,
    const int*   __restrict__ h_ids,
    const int*   __restrict__ t_ids,
    const int*   __restrict__ ws,
    float*       __restrict__ out)
{
    __shared__ char smem[43648];
    unsigned short* Rb = (unsigned short*)smem;
    unsigned short* Hb = (unsigned short*)(smem + 34816);
    int*  sidx = (int*)(smem + 43520);
    float* Pp  = (float*)smem;

    const int cid = blockIdx.x;
    if (cid >= ws[1000]) return;
    const int e    = ws[1024 + cid];
    const int r    = e >> 20;
    const int base = (e >> 6) & 16383;
    const int len  = e & 63;
    const int* sorted = ws + 2048;

    const int tid  = threadIdx.x;
    const int lane = tid & 63;
    const int w    = tid >> 6;

    if (tid < CH) {
        int tc = tid < len ? tid : len - 1;
        sidx[tid] = sorted[base + tc];
    }
    __syncthreads();

    // ---- stage R (64KB fp32 -> 32KB bf16, padded stride 136)
    const float4* Rg = (const float4*)ent + ((long)r << 12);
    #pragma unroll
    for (int s = 0; s < 16; ++s) {
        int g = s * 256 + tid;
        int row = g >> 5, c4 = g & 31;
        float4 v = Rg[g];
        ushort4 b; b.x = f2bf(v.x); b.y = f2bf(v.y); b.z = f2bf(v.z); b.w = f2bf(v.w);
        *(ushort4*)(Rb + row * 136 + c4 * 4) = b;
    }
    // ---- stage h rows (32 x 512B fp32 -> bf16)
    #pragma unroll
    for (int s = 0; s < 4; ++s) {
        int g = s * 256 + tid;
        int trow = g >> 5, c4 = g & 31;
        int hid = h_ids[sidx[trow]];
        float4 v = ((const float4*)ent)[((long)hid << 5) + c4];
        ushort4 b; b.x = f2bf(v.x); b.y = f2bf(v.y); b.z = f2bf(v.z); b.w = f2bf(v.w);
        *(ushort4*)(Hb + trow * 136 + c4 * 4) = b;
    }
    __syncthreads();

    // ---- MFMA: wave w owns output cols [w*32, w*32+32)
    const int q = lane >> 4, c = lane & 15;
    const unsigned short* A0p = Hb + c * 136 + q * 8;
    const unsigned short* A1p = Hb + (c + 16) * 136 + q * 8;
    const unsigned short* B0p = Rb + (w * 32 + c) * 136 + q * 8;
    const unsigned short* B1p = Rb + (w * 32 + 16 + c) * 136 + q * 8;

    f32x4 a00 = {0.f,0.f,0.f,0.f}, a01 = a00, a10 = a00, a11 = a00;
    #pragma unroll
    for (int ks = 0; ks < 4; ++ks) {
        bf16x8 A0 = *(const bf16x8*)(A0p + ks * 32);
        bf16x8 A1 = *(const bf16x8*)(A1p + ks * 32);
        bf16x8 B0 = *(const bf16x8*)(B0p + ks * 32);
        bf16x8 B1 = *(const bf16x8*)(B1p + ks * 32);
        a00 = __builtin_amdgcn_mfma_f32_16x16x32_bf16(A0, B0, a00, 0, 0, 0);
        a01 = __builtin_amdgcn_mfma_f32_16x16x32_bf16(A0, B1, a01, 0, 0, 0);
        a10 = __builtin_amdgcn_mfma_f32_16x16x32_bf16(A1, B0, a10, 0, 0, 0);
        a11 = __builtin_amdgcn_mfma_f32_16x16x32_bf16(A1, B1, a11, 0, 0, 0);
    }
    __syncthreads();   // Rb dead; Pp aliases it

    // ---- write prod to LDS: D layout col=lane&15, row=(lane>>4)*4+reg
    #pragma unroll
    for (int reg = 0; reg < 4; ++reg) {
        int m0 = q * 4 + reg;
        Pp[m0 * 132        + w * 32      + c] = a00[reg];
        Pp[m0 * 132        + w * 32 + 16 + c] = a01[reg];
        Pp[(m0 + 16) * 132 + w * 32      + c] = a10[reg];
        Pp[(m0 + 16) * 132 + w * 32 + 16 + c] = a11[reg];
    }
    __syncthreads();

    // ---- epilogue: out = sqrt(2 - 2*<p,t>/(|p||t|)); wave w owns triples w*8..+7
    #pragma unroll
    for (int tt = 0; tt < 8; ++tt) {
        int t   = w * 8 + tt;
        int idx = sidx[t];
        int trow = __builtin_amdgcn_readfirstlane(t_ids[idx]);
        const float* tv = ent + ((long)trow << 7);
        float tv0 = tv[lane], tv1 = tv[lane + 64];
        float p0 = Pp[t * 132 + lane], p1 = Pp[t * 132 + 64 + lane];
        float sp  = p0 * p0 + p1 * p1;
        float st  = tv0 * tv0 + tv1 * tv1;
        float spt = p0 * tv0 + p1 * tv1;
        #pragma unroll
        for (int m = 32; m >= 1; m >>= 1) {
            sp  += __shfl_xor(sp,  m, 64);
            st  += __shfl_xor(st,  m, 64);
            spt += __shfl_xor(spt, m, 64);
        }
        if (lane == 0 && t < len) {
            float npn = fmaxf(sqrtf(sp), EPS);
            float ntn = fmaxf(sqrtf(st), EPS);
            float v   = 2.0f - 2.0f * (spt / (npn * ntn));
            out[idx] = sqrtf(fmaxf(v, 0.0f));
        }
    }
}

extern "C" void kernel_launch(void* const* d_in, const int* in_sizes, int n_in,
                              void* d_out, int out_size, void* d_ws, size_t ws_size,
                              hipStream_t stream) {
    const float* ent   = (const float*)d_in[0];
    const int*   h_ids = (const int*)d_in[1];
    const int*   r_typ = (const int*)d_in[2];
    const int*   t_ids = (const int*)d_in[3];
    float* out = (float*)d_out;
    int*   ws  = (int*)d_ws;
    const int n = in_sizes[1];

    hipMemsetAsync(ws, 0, 4096, stream);   // counts + ticket + cursors
    hipLaunchKernelGGL(k_prep,  dim3(PREPB),    dim3(256), 0, stream, r_typ, ws, n);
    hipLaunchKernelGGL(relgemm, dim3(MAXCHUNK), dim3(256), 0, stream,
                       ent, h_ids, t_ids, ws, out);
}

// Round 8
// 119.305 us; speedup vs baseline: 1.0867x; 1.0242x over previous
//
#include <hip/hip_runtime.h>

#define RELS 237
#define DIM 128
#define CH 32           // triples per chunk
#define MAXCHUNK 742    // sum ceil(c_r/32) <= (16384 + 237*31)/32
#define PREPB 64        // prep grid: 64 blocks, trivially co-resident
#define EPS 1e-12f

typedef __attribute__((ext_vector_type(8))) short bf16x8;
typedef __attribute__((ext_vector_type(4))) float f32x4;

// ws layout (int32):
//   [0, 237)     : per-relation counts   (zeroed by memsetAsync)
//   [254]        : barrier ticket        (zeroed)
//   [512, 749)   : per-relation scatter cursors (zeroed)
//   [1000]       : n_chunks
//   [1024, 1024+MAXCHUNK) : chunk worklist, entry = (r<<20)|(base<<6)|len
//   [2048,  2048+N)  : triple indices grouped by relation
//   [18432, 18432+N) : pre-gathered h_ids, same order
//   [34816, 34816+N) : pre-gathered t_ids, same order
// memsetAsync zeroes [0, 1024) ints = 4096 B.

__device__ __forceinline__ unsigned short f2bf(float f) {
    unsigned int u = __float_as_uint(f);
    u = (u + 0x7fffu + ((u >> 16) & 1u)) >> 16;   // RNE
    return (unsigned short)u;
}

// Single prep kernel, 64 blocks x 256 threads:
//   A: LDS histogram -> one global atomicAdd per (block, relation)
//   spin barrier (64 co-resident blocks -> deadlock-free)
//   B: coherent re-read + local LDS scan (redundant per block);
//      block 0 emits chunk worklist + n_chunks
//   C: grid-stride scatter of (idx, h_id, t_id) -- h/t pre-gathered here
//      with coalesced reads so relgemm has one fewer dependent gather level.
__global__ __launch_bounds__(256) void k_prep(const int* __restrict__ r_typ,
                                              const int* __restrict__ h_ids,
                                              const int* __restrict__ t_ids,
                                              int* __restrict__ ws, int n) {
    __shared__ int hist[256];
    __shared__ int offs[256];
    __shared__ int scn[256];
    const int t = threadIdx.x;
    hist[t] = 0;
    __syncthreads();

    // ---- A: count
    for (int i = blockIdx.x * 256 + t; i < n; i += PREPB * 256)
        atomicAdd(&hist[r_typ[i]], 1);
    __syncthreads();
    if (t < RELS && hist[t] > 0) atomicAdd(&ws[t], hist[t]);

    // ---- barrier
    __syncthreads();
    __threadfence();
    if (t == 0) {
        atomicAdd(&ws[254], 1);
        while (atomicAdd(&ws[254], 0) < PREPB) __builtin_amdgcn_s_sleep(2);
    }
    __syncthreads();
    __threadfence();

    // ---- B: coherent re-read + local scan
    const int c = (t < RELS) ? atomicAdd(&ws[t], 0) : 0;
    scn[t] = c; __syncthreads();
    #pragma unroll
    for (int off = 1; off < 256; off <<= 1) {
        int v = (t >= off) ? scn[t - off] : 0;
        __syncthreads();
        scn[t] += v; __syncthreads();
    }
    offs[t] = scn[t] - c;
    __syncthreads();

    if (blockIdx.x == 0) {
        const int nch = (c + CH - 1) >> 5;
        scn[t] = nch; __syncthreads();
        #pragma unroll
        for (int off = 1; off < 256; off <<= 1) {
            int v = (t >= off) ? scn[t - off] : 0;
            __syncthreads();
            scn[t] += v; __syncthreads();
        }
        const int choff = scn[t] - nch;
        if (t == 255) ws[1000] = scn[255];
        for (int j = 0; j < nch; ++j) {
            int cb  = offs[t] + j * CH;
            int len = c - j * CH; if (len > CH) len = CH;
            ws[1024 + choff + j] = (t << 20) | (cb << 6) | len;
        }
    }

    // ---- C: scatter idx + pre-gathered h_id/t_id
    for (int i = blockIdx.x * 256 + t; i < n; i += PREPB * 256) {
        int rr  = r_typ[i];
        int hi  = h_ids[i];
        int ti  = t_ids[i];
        int pos = offs[rr] + atomicAdd(&ws[512 + rr], 1);
        ws[2048  + pos] = i;
        ws[18432 + pos] = hi;
        ws[34816 + pos] = ti;
    }
}

// One workgroup per 32-triple chunk of one relation. MFMA bf16 16x16x32,
// fp32 accumulate. A = h (M=32), B = R^T via direct row reads.
// LDS: Rb bf16[128][136] @0 (34816B), Hb bf16[32][136] @34816 (8704B),
// sidx @43520 (128B), tRow @43648 (128B); Pp f32[32][132] aliases dead Rb.
// 43.8KB/block -> 3 blocks/CU; all 742 blocks co-resident.
__global__ __launch_bounds__(256, 3) void relgemm(
    const float* __restrict__ ent,
    const int*   __restrict__ ws,
    float*       __restrict__ out)
{
    __shared__ char smem[43776];
    unsigned short* Rb = (unsigned short*)smem;
    unsigned short* Hb = (unsigned short*)(smem + 34816);
    int*  sidx = (int*)(smem + 43520);
    int*  tRow = (int*)(smem + 43648);
    float* Pp  = (float*)smem;

    const int cid = blockIdx.x;
    if (cid >= ws[1000]) return;
    const int e    = ws[1024 + cid];
    const int r    = e >> 20;
    const int base = (e >> 6) & 16383;
    const int len  = e & 63;
    const int* sortedIdx = ws + 2048;
    const int* shid      = ws + 18432;
    const int* stid      = ws + 34816;

    const int tid  = threadIdx.x;
    const int lane = tid & 63;
    const int w    = tid >> 6;

    // issue chunk-metadata loads first (latency overlapped with staging)
    if (tid < CH) {
        int tc = tid < len ? tid : len - 1;
        sidx[tid] = sortedIdx[base + tc];
        tRow[tid] = stid[base + tc];
    }

    // ---- stage h rows (32 x 512B fp32 -> bf16); h_id read directly from ws
    // (pre-gathered by prep -> no LDS dependency, no extra gather level)
    #pragma unroll
    for (int s = 0; s < 4; ++s) {
        int g = s * 256 + tid;
        int trow = g >> 5, c4 = g & 31;
        int tc = trow < len ? trow : len - 1;
        int hid = shid[base + tc];
        float4 v = ((const float4*)ent)[((long)hid << 5) + c4];
        ushort4 b; b.x = f2bf(v.x); b.y = f2bf(v.y); b.z = f2bf(v.z); b.w = f2bf(v.w);
        *(ushort4*)(Hb + trow * 136 + c4 * 4) = b;
    }
    // ---- stage R (64KB fp32 -> 32KB bf16, padded stride 136)
    const float4* Rg = (const float4*)ent + ((long)r << 12);
    #pragma unroll
    for (int s = 0; s < 16; ++s) {
        int g = s * 256 + tid;
        int row = g >> 5, c4 = g & 31;
        float4 v = Rg[g];
        ushort4 b; b.x = f2bf(v.x); b.y = f2bf(v.y); b.z = f2bf(v.z); b.w = f2bf(v.w);
        *(ushort4*)(Rb + row * 136 + c4 * 4) = b;
    }
    __syncthreads();

    // ---- MFMA: wave w owns output cols [w*32, w*32+32)
    const int q = lane >> 4, c = lane & 15;
    const unsigned short* A0p = Hb + c * 136 + q * 8;
    const unsigned short* A1p = Hb + (c + 16) * 136 + q * 8;
    const unsigned short* B0p = Rb + (w * 32 + c) * 136 + q * 8;
    const unsigned short* B1p = Rb + (w * 32 + 16 + c) * 136 + q * 8;

    f32x4 a00 = {0.f,0.f,0.f,0.f}, a01 = a00, a10 = a00, a11 = a00;
    #pragma unroll
    for (int ks = 0; ks < 4; ++ks) {
        bf16x8 A0 = *(const bf16x8*)(A0p + ks * 32);
        bf16x8 A1 = *(const bf16x8*)(A1p + ks * 32);
        bf16x8 B0 = *(const bf16x8*)(B0p + ks * 32);
        bf16x8 B1 = *(const bf16x8*)(B1p + ks * 32);
        a00 = __builtin_amdgcn_mfma_f32_16x16x32_bf16(A0, B0, a00, 0, 0, 0);
        a01 = __builtin_amdgcn_mfma_f32_16x16x32_bf16(A0, B1, a01, 0, 0, 0);
        a10 = __builtin_amdgcn_mfma_f32_16x16x32_bf16(A1, B0, a10, 0, 0, 0);
        a11 = __builtin_amdgcn_mfma_f32_16x16x32_bf16(A1, B1, a11, 0, 0, 0);
    }
    __syncthreads();   // Rb dead; Pp aliases it

    // ---- write prod to LDS: D layout col=lane&15, row=(lane>>4)*4+reg
    #pragma unroll
    for (int reg = 0; reg < 4; ++reg) {
        int m0 = q * 4 + reg;
        Pp[m0 * 132        + w * 32      + c] = a00[reg];
        Pp[m0 * 132        + w * 32 + 16 + c] = a01[reg];
        Pp[(m0 + 16) * 132 + w * 32      + c] = a10[reg];
        Pp[(m0 + 16) * 132 + w * 32 + 16 + c] = a11[reg];
    }
    __syncthreads();

    // ---- epilogue: prefetch ALL t-rows/prod into registers (independent
    // loads, one latency wait), then run the shuffle reductions.
    float p0v[8], p1v[8], t0v[8], t1v[8];
    #pragma unroll
    for (int tt = 0; tt < 8; ++tt) {
        int t = w * 8 + tt;
        int trow = tRow[t];
        const float* tv = ent + ((long)trow << 7);
        t0v[tt] = tv[lane];
        t1v[tt] = tv[lane + 64];
        p0v[tt] = Pp[t * 132 + lane];
        p1v[tt] = Pp[t * 132 + 64 + lane];
    }
    #pragma unroll
    for (int tt = 0; tt < 8; ++tt) {
        int t   = w * 8 + tt;
        float p0 = p0v[tt], p1 = p1v[tt];
        float tv0 = t0v[tt], tv1 = t1v[tt];
        float sp  = p0 * p0 + p1 * p1;
        float st  = tv0 * tv0 + tv1 * tv1;
        float spt = p0 * tv0 + p1 * tv1;
        #pragma unroll
        for (int m = 32; m >= 1; m >>= 1) {
            sp  += __shfl_xor(sp,  m, 64);
            st  += __shfl_xor(st,  m, 64);
            spt += __shfl_xor(spt, m, 64);
        }
        if (lane == 0 && t < len) {
            float npn = fmaxf(sqrtf(sp), EPS);
            float ntn = fmaxf(sqrtf(st), EPS);
            float v   = 2.0f - 2.0f * (spt / (npn * ntn));
            out[sidx[t]] = sqrtf(fmaxf(v, 0.0f));
        }
    }
}

extern "C" void kernel_launch(void* const* d_in, const int* in_sizes, int n_in,
                              void* d_out, int out_size, void* d_ws, size_t ws_size,
                              hipStream_t stream) {
    const float* ent   = (const float*)d_in[0];
    const int*   h_ids = (const int*)d_in[1];
    const int*   r_typ = (const int*)d_in[2];
    const int*   t_ids = (const int*)d_in[3];
    float* out = (float*)d_out;
    int*   ws  = (int*)d_ws;
    const int n = in_sizes[1];

    hipMemsetAsync(ws, 0, 4096, stream);   // counts + ticket + cursors
    hipLaunchKernelGGL(k_prep,  dim3(PREPB),    dim3(256), 0, stream,
                       r_typ, h_ids, t_ids, ws, n);
    hipLaunchKernelGGL(relgemm, dim3(MAXCHUNK), dim3(256), 0, stream,
                       ent, ws, out);
}